// Round 11
// baseline (1543.041 us; speedup 1.0000x reference)
//
#include <hip/hip_runtime.h>
#include <math.h>

#define BATCH 256
#define SEQ   2048
#define HID   128
#define NTHR  256
#define VOCAB 50000

typedef _Float16 v2h __attribute__((ext_vector_type(2)));

template<int CTRL>
__device__ __forceinline__ float dpp_movf(float x) {
    return __builtin_bit_cast(float,
        __builtin_amdgcn_update_dpp(0, __builtin_bit_cast(int, x),
                                    CTRL, 0xF, 0xF, false));
}
__device__ __forceinline__ float quad_reduce(float x) {
    x += dpp_movf<0xB1>(x);   // + lane^1
    x += dpp_movf<0x4E>(x);   // + lane^2
    return x;                 // full quad sum in all 4 lanes
}
__device__ __forceinline__ float fast_rcp(float x) { return __builtin_amdgcn_rcpf(x); }
__device__ __forceinline__ float dot2(v2h a, v2h b, float c) {
    return __builtin_amdgcn_fdot2(a, b, c, false);   // v_dot2_f32_f16
}
#define BCH(u) __builtin_bit_cast(v2h, (u))

// lgkmcnt-only barrier (R9): LDS visibility without draining global loads.
__device__ __forceinline__ void barrier_lds() {
    asm volatile("s_waitcnt lgkmcnt(0)\n\ts_barrier" ::: "memory");
}
// Ablation: SAME wait, NO barrier. LDS values race (timing-valid, output unused).
__device__ __forceinline__ void wait_lds_only() {
    asm volatile("s_waitcnt lgkmcnt(0)" ::: "memory");
}

// ---------------- Y = emb @ W_ih[0] + b[0]  (f16 out) ----------------
__global__ __launch_bounds__(512, 2) void emb_proj_kernel(
    const float* __restrict__ emb, const float* __restrict__ W_ih,
    const float* __restrict__ bias, _Float16* __restrict__ Y)
{
    const int tid  = threadIdx.x;
    const int wave = tid >> 6;
    const int lane = tid & 63;
    const int j    = wave * 16 + (lane >> 2);
    const int q    = lane & 3;

    __shared__ __align__(16) _Float16 xr[HID];

    v2h w[16];
#pragma unroll
    for (int i = 0; i < 16; ++i) {
        const int k = q * 32 + 2 * i;
        w[i] = v2h{(_Float16)W_ih[k * HID + j], (_Float16)W_ih[(k + 1) * HID + j]};
    }
    const float bj = bias[j];
    const float4* embf4 = (const float4*)emb;

    for (int r = blockIdx.x; r < VOCAB; r += gridDim.x) {
        if (tid < 32) {
            float4 v = embf4[(size_t)r * 32 + tid];
            uint a01 = __builtin_bit_cast(uint, __builtin_amdgcn_cvt_pkrtz(v.x, v.y));
            uint a23 = __builtin_bit_cast(uint, __builtin_amdgcn_cvt_pkrtz(v.z, v.w));
            ((uint2*)&xr[0])[tid] = uint2{a01, a23};
        }
        __syncthreads();
        const uint4* xp = (const uint4*)&xr[0] + q * 4;
        float acc = 0.f;
#pragma unroll
        for (int i = 0; i < 4; ++i) {
            const uint4 xu = xp[i];
            acc = dot2(BCH(xu.x), w[4*i+0], acc);
            acc = dot2(BCH(xu.y), w[4*i+1], acc);
            acc = dot2(BCH(xu.z), w[4*i+2], acc);
            acc = dot2(BCH(xu.w), w[4*i+3], acc);
        }
        acc = quad_reduce(acc) + bj;
        if (q == 0) Y[(size_t)r * HID + j] = (_Float16)acc;
        __syncthreads();
    }
}

// ---------------- recurrent kernel body (templated on SYNC) ----------------
// SYNC=1: exact R9 kernel. SYNC=0: s_barrier removed (timing ablation; LDS
// values race; result written to wsout, never validated).
template<int SYNC>
__device__ __forceinline__ void rnn_body(
    const int* __restrict__ x, const int* __restrict__ lengths,
    const _Float16* __restrict__ Y, const float* __restrict__ W_ih,
    const float* __restrict__ W_hh, const float* __restrict__ bias,
    const float* __restrict__ cls_w, const float* __restrict__ cls_b,
    float* __restrict__ outp)
{
    const int b    = blockIdx.x;
    const int tid  = threadIdx.x;
    const int wave = tid >> 6;
    const int lane = tid & 63;
    const int jg   = wave * 16 + (lane >> 2);
    const int q    = lane & 3;
    const int jm   = lane & 1;
    const int isl1 = (lane >> 1) & 1;
    const int jt   = 2 * jg + jm;

    __shared__ int xids[SEQ];
    __shared__ __align__(16) _Float16 h0h[2][HID];
    __shared__ __align__(16) _Float16 h1h[2][HID];
    __shared__ __align__(16) float    red[HID];

    const int len   = lengths[b];
    const int lenm1 = len - 1;
    const float LOG2E2 = 2.88539008177793f;

    for (int i = tid; i < SEQ; i += NTHR) xids[i] = x[b * SEQ + i];
    if (tid < HID) {
        h0h[0][tid] = (_Float16)0.f; h0h[1][tid] = (_Float16)0.f;
        h1h[0][tid] = (_Float16)0.f; h1h[1][tid] = (_Float16)0.f;
    }

    v2h whh0[2][16], wih1[2][16], whh1[2][16];
#pragma unroll
    for (int i = 0; i < 16; ++i) {
        const int k = 32 * q + 2 * i;
#pragma unroll
        for (int m = 0; m < 2; ++m) {
            const int j = 2 * jg + m;
            whh0[m][i] = v2h{(_Float16)W_hh[k * HID + j],
                             (_Float16)W_hh[(k + 1) * HID + j]};
            wih1[m][i] = v2h{(_Float16)W_ih[HID * HID + k * HID + j],
                             (_Float16)W_ih[HID * HID + (k + 1) * HID + j]};
            whh1[m][i] = v2h{(_Float16)W_hh[HID * HID + k * HID + j],
                             (_Float16)W_hh[HID * HID + (k + 1) * HID + j]};
        }
    }
    const float b1K = bias[HID + jt] * LOG2E2;

    __syncthreads();

    _Float16 zA = Y[(size_t)xids[0] * HID + jt];
    _Float16 zB = Y[(size_t)xids[min(1, lenm1)] * HID + jt];

    int ph = 0, pf = 0;

#define TANH_PRE(ZK) (1.0f - 2.0f * fast_rcp(__builtin_amdgcn_exp2f(ZK) + 1.0f))

#define DO_PHASE(RD, WR, ZREG)                                              \
    {                                                                       \
        const uint4* h0p = (const uint4*)&h0h[RD][0] + q * 4;               \
        const uint4* h1p = (const uint4*)&h1h[RD][0] + q * 4;               \
        const float zcK = (float)ZREG * LOG2E2;                             \
        {                                                                   \
            const int tn = xids[min(ph + 2, lenm1)];                        \
            ZREG = Y[(size_t)tn * HID + jt];                                \
        }                                                                   \
        float a0_0 = 0.f, a0_1 = 0.f;                                       \
        float aA_0 = 0.f, aA_1 = 0.f;                                       \
        float aB_0 = 0.f, aB_1 = 0.f;                                       \
        _Pragma("unroll")                                                   \
        for (int c = 0; c < 4; ++c) {                                       \
            const uint4 hu = h0p[c];                                        \
            const uint4 gu = h1p[c];                                        \
            a0_0 = dot2(BCH(hu.x), whh0[0][4*c+0], a0_0);                   \
            a0_0 = dot2(BCH(hu.y), whh0[0][4*c+1], a0_0);                   \
            a0_0 = dot2(BCH(hu.z), whh0[0][4*c+2], a0_0);                   \
            a0_0 = dot2(BCH(hu.w), whh0[0][4*c+3], a0_0);                   \
            a0_1 = dot2(BCH(hu.x), whh0[1][4*c+0], a0_1);                   \
            a0_1 = dot2(BCH(hu.y), whh0[1][4*c+1], a0_1);                   \
            a0_1 = dot2(BCH(hu.z), whh0[1][4*c+2], a0_1);                   \
            a0_1 = dot2(BCH(hu.w), whh0[1][4*c+3], a0_1);                   \
            aA_0 = dot2(BCH(hu.x), wih1[0][4*c+0], aA_0);                   \
            aA_0 = dot2(BCH(hu.y), wih1[0][4*c+1], aA_0);                   \
            aA_0 = dot2(BCH(hu.z), wih1[0][4*c+2], aA_0);                   \
            aA_0 = dot2(BCH(hu.w), wih1[0][4*c+3], aA_0);                   \
            aA_1 = dot2(BCH(hu.x), wih1[1][4*c+0], aA_1);                   \
            aA_1 = dot2(BCH(hu.y), wih1[1][4*c+1], aA_1);                   \
            aA_1 = dot2(BCH(hu.z), wih1[1][4*c+2], aA_1);                   \
            aA_1 = dot2(BCH(hu.w), wih1[1][4*c+3], aA_1);                   \
            aB_0 = dot2(BCH(gu.x), whh1[0][4*c+0], aB_0);                   \
            aB_0 = dot2(BCH(gu.y), whh1[0][4*c+1], aB_0);                   \
            aB_0 = dot2(BCH(gu.z), whh1[0][4*c+2], aB_0);                   \
            aB_0 = dot2(BCH(gu.w), whh1[0][4*c+3], aB_0);                   \
            aB_1 = dot2(BCH(gu.x), whh1[1][4*c+0], aB_1);                   \
            aB_1 = dot2(BCH(gu.y), whh1[1][4*c+1], aB_1);                   \
            aB_1 = dot2(BCH(gu.z), whh1[1][4*c+2], aB_1);                   \
            aB_1 = dot2(BCH(gu.w), whh1[1][4*c+3], aB_1);                   \
        }                                                                   \
        float s0_0 = quad_reduce(a0_0);                                     \
        float s0_1 = quad_reduce(a0_1);                                     \
        float s1_0 = quad_reduce(aA_0 + aB_0);                              \
        float s1_1 = quad_reduce(aA_1 + aB_1);                              \
        const float sj  = jm  ? (isl1 ? s1_1 : s0_1) : (isl1 ? s1_0 : s0_0);\
        const float cj  = isl1 ? b1K : zcK;                                 \
        const float t   = TANH_PRE(__builtin_fmaf(sj, LOG2E2, cj));         \
        if (!isl1) { if (ph < len) h0h[WR][jt] = (_Float16)t; }             \
        else       { if (ph >= 1)  h1h[WR][jt] = (_Float16)t; }             \
        if (SYNC) barrier_lds(); else wait_lds_only();                      \
    }

    for (;;) {
        DO_PHASE(0, 1, zA)
        ++ph;
        if (ph > len) { pf = 1; break; }
        DO_PHASE(1, 0, zB)
        ++ph;
        if (ph > len) { pf = 0; break; }
    }
#undef DO_PHASE
#undef TANH_PRE

    if (tid < HID) red[tid] = (float)h1h[pf][tid] * cls_w[tid];
    __syncthreads();
    if (tid == 0) {
        float s = 0.f;
        for (int i = 0; i < HID; ++i) s += red[i];
        s += cls_b[0];
        outp[b] = fast_rcp(1.0f + __expf(-s));
    }
}

__global__ __launch_bounds__(NTHR, 1) void rnn_ctrl_kernel(
    const int* __restrict__ x, const int* __restrict__ lengths,
    const _Float16* __restrict__ Y, const float* __restrict__ W_ih,
    const float* __restrict__ W_hh, const float* __restrict__ bias,
    const float* __restrict__ cls_w, const float* __restrict__ cls_b,
    float* __restrict__ out)
{
    rnn_body<1>(x, lengths, Y, W_ih, W_hh, bias, cls_w, cls_b, out);
}

__global__ __launch_bounds__(NTHR, 1) void rnn_nobar_kernel(
    const int* __restrict__ x, const int* __restrict__ lengths,
    const _Float16* __restrict__ Y, const float* __restrict__ W_ih,
    const float* __restrict__ W_hh, const float* __restrict__ bias,
    const float* __restrict__ cls_w, const float* __restrict__ cls_b,
    float* __restrict__ wsout)
{
    rnn_body<0>(x, lengths, Y, W_ih, W_hh, bias, cls_w, cls_b, wsout);
}

extern "C" void kernel_launch(void* const* d_in, const int* in_sizes, int n_in,
                              void* d_out, int out_size, void* d_ws, size_t ws_size,
                              hipStream_t stream) {
    const int*   x       = (const int*)  d_in[0];
    const int*   lengths = (const int*)  d_in[1];
    const float* emb     = (const float*)d_in[2];
    const float* W_ih    = (const float*)d_in[3];
    const float* W_hh    = (const float*)d_in[4];
    const float* bias    = (const float*)d_in[5];
    const float* cls_w   = (const float*)d_in[6];
    const float* cls_b   = (const float*)d_in[7];
    float*       out     = (float*)      d_out;

    _Float16* Yws = (_Float16*)d_ws;     // 50000*128*2 B = 12.8 MB

    emb_proj_kernel<<<2048, 512, 0, stream>>>(emb, W_ih, bias, Yws);
    rnn_ctrl_kernel<<<BATCH, NTHR, 0, stream>>>(
        x, lengths, Yws, W_ih, W_hh, bias, cls_w, cls_b, out);
    // Ablation: no-barrier variant; scribbles 256 floats over the head of Y,
    // which the next replay's emb_proj_kernel fully rewrites. d_out untouched.
    rnn_nobar_kernel<<<BATCH, NTHR, 0, stream>>>(
        x, lengths, Yws, W_ih, W_hh, bias, cls_w, cls_b, (float*)d_ws);
}

// Round 12
// 882.071 us; speedup vs baseline: 1.7493x; 1.7493x over previous
//
#include <hip/hip_runtime.h>
#include <math.h>

#define BATCH 256
#define SEQ   2048
#define HID   128
#define NTHR  512
#define VOCAB 50000

typedef _Float16 v2h __attribute__((ext_vector_type(2)));

template<int CTRL>
__device__ __forceinline__ float dpp_movf(float x) {
    return __builtin_bit_cast(float,
        __builtin_amdgcn_update_dpp(0, __builtin_bit_cast(int, x),
                                    CTRL, 0xF, 0xF, false));
}
__device__ __forceinline__ float quad_reduce(float x) {
    x += dpp_movf<0xB1>(x);   // + lane^1
    x += dpp_movf<0x4E>(x);   // + lane^2
    return x;                 // full quad sum in all 4 lanes
}
__device__ __forceinline__ float fast_rcp(float x) { return __builtin_amdgcn_rcpf(x); }
__device__ __forceinline__ float dot2(v2h a, v2h b, float c) {
    return __builtin_amdgcn_fdot2(a, b, c, false);   // v_dot2_f32_f16
}
#define BCH(u) __builtin_bit_cast(v2h, (u))

// lgkmcnt-only barrier: LDS visibility without draining global loads.
__device__ __forceinline__ void barrier_lds() {
    asm volatile("s_waitcnt lgkmcnt(0)\n\ts_barrier" ::: "memory");
}

// ---------------- Y = emb @ W_ih[0] + b[0]  (f16 out) ----------------
__global__ __launch_bounds__(512, 2) void emb_proj_kernel(
    const float* __restrict__ emb, const float* __restrict__ W_ih,
    const float* __restrict__ bias, _Float16* __restrict__ Y)
{
    const int tid  = threadIdx.x;
    const int wave = tid >> 6;
    const int lane = tid & 63;
    const int j    = wave * 16 + (lane >> 2);
    const int q    = lane & 3;

    __shared__ __align__(16) _Float16 xr[HID];

    v2h w[16];
#pragma unroll
    for (int i = 0; i < 16; ++i) {
        const int k = q * 32 + 2 * i;
        w[i] = v2h{(_Float16)W_ih[k * HID + j], (_Float16)W_ih[(k + 1) * HID + j]};
    }
    const float bj = bias[j];
    const float4* embf4 = (const float4*)emb;

    for (int r = blockIdx.x; r < VOCAB; r += gridDim.x) {
        if (tid < 32) {
            float4 v = embf4[(size_t)r * 32 + tid];
            uint a01 = __builtin_bit_cast(uint, __builtin_amdgcn_cvt_pkrtz(v.x, v.y));
            uint a23 = __builtin_bit_cast(uint, __builtin_amdgcn_cvt_pkrtz(v.z, v.w));
            ((uint2*)&xr[0])[tid] = uint2{a01, a23};
        }
        __syncthreads();
        const uint4* xp = (const uint4*)&xr[0] + q * 4;
        float acc = 0.f;
#pragma unroll
        for (int i = 0; i < 4; ++i) {
            const uint4 xu = xp[i];
            acc = dot2(BCH(xu.x), w[4*i+0], acc);
            acc = dot2(BCH(xu.y), w[4*i+1], acc);
            acc = dot2(BCH(xu.z), w[4*i+2], acc);
            acc = dot2(BCH(xu.w), w[4*i+3], acc);
        }
        acc = quad_reduce(acc) + bj;
        if (q == 0) Y[(size_t)r * HID + j] = (_Float16)acc;
        __syncthreads();
    }
}

// ------------- wave-specialized recurrent kernel (layer-split) -------------
// 8 waves. Waves 0-3 (A): layer-0 recurrence + feed-forward g.
//   phase p: h0(p) = tanh(Whh0 h0(p-1) + Y[tok p]);  g(p-1) = Wih1 h0(p-1)
//   (both matvecs read the SAME h0(p-1) LDS slice -> 4 ds_reads, 32 dot2)
// Waves 4-7 (B): layer-1 recurrence, lag 2:
//   phase p: h1(p-2) = tanh(g(p-2) + Whh1 h1(p-3) + b1)   [16 dot2 + g read]
// Thread (jg, q): cols {2jg, 2jg+1}, k-quarter q. After quad_reduce, quad
// lane (jm, sel): A tasks = (col, h0-vs-g); B tasks = (col, write-vs-idle).
// One lgkm barrier per phase; phases p = 0 .. len+1.
__global__ __launch_bounds__(NTHR, 1) void rnn_split_kernel(
    const int*      __restrict__ x,        // [B, T]
    const int*      __restrict__ lengths,  // [B]
    const _Float16* __restrict__ Y,        // [VOCAB, 128] = emb@Wih0 + b0
    const float*    __restrict__ W_ih,     // [2, 128, 128] (layer 1 used)
    const float*    __restrict__ W_hh,     // [2, 128, 128]
    const float*    __restrict__ bias,     // [2, 128] (layer 1 used)
    const float*    __restrict__ cls_w,    // [128]
    const float*    __restrict__ cls_b,    // [1]
    float*          __restrict__ out)      // [B]
{
    const int b    = blockIdx.x;
    const int tid  = threadIdx.x;
    const int wave = tid >> 6;
    const int lane = tid & 63;
    const bool isA = wave < 4;
    const int wl   = isA ? wave : (wave - 4);
    const int jg   = wl * 16 + (lane >> 2);     // [0,64)
    const int q    = lane & 3;                  // k-quarter
    const int jm   = lane & 1;                  // task col select
    const int sel  = (lane >> 1) & 1;           // task output select
    const int jt   = 2 * jg + jm;

    __shared__ int xids[SEQ];                        // 8 KB
    __shared__ __align__(16) _Float16 h0h[2][HID];
    __shared__ __align__(16) _Float16 h1h[2][HID];
    __shared__ __align__(16) float    gh[2][HID];    // g stream, f32
    __shared__ __align__(16) float    red[HID];

    const int len   = lengths[b];
    const int lenm1 = len - 1;
    const int LIM   = len + 1;                       // phases 0..len+1
    const float LOG2E2 = 2.88539008177793f;          // 2*log2(e)

    for (int i = tid; i < SEQ; i += NTHR) xids[i] = x[b * SEQ + i];
    if (tid < HID) {
        h0h[0][tid] = (_Float16)0.f; h0h[1][tid] = (_Float16)0.f;
        h1h[0][tid] = (_Float16)0.f; h1h[1][tid] = (_Float16)0.f;
        gh[0][tid]  = 0.f;           gh[1][tid]  = 0.f;
    }
    __syncthreads();                                 // staging visible to all

    int ph = 0, pf = 0;

#define TANH_PRE(ZK) (1.0f - 2.0f * fast_rcp(__builtin_amdgcn_exp2f(ZK) + 1.0f))

    if (isA) {
        // ---- A: weights Whh0 + Wih1 (layer-1 input matrix), cols 2jg,2jg+1 ----
        v2h whh0[2][16], wg[2][16];
#pragma unroll
        for (int i = 0; i < 16; ++i) {
            const int k = 32 * q + 2 * i;
#pragma unroll
            for (int m = 0; m < 2; ++m) {
                const int j = 2 * jg + m;
                whh0[m][i] = v2h{(_Float16)W_hh[k * HID + j],
                                 (_Float16)W_hh[(k + 1) * HID + j]};
                wg[m][i]   = v2h{(_Float16)W_ih[HID * HID + k * HID + j],
                                 (_Float16)W_ih[HID * HID + (k + 1) * HID + j]};
            }
        }
        _Float16 zA = Y[(size_t)xids[0] * HID + jt];
        _Float16 zB = Y[(size_t)xids[min(1, lenm1)] * HID + jt];

#define A_PHASE(RD, WR, ZREG)                                               \
    {                                                                       \
        const uint4* h0p = (const uint4*)&h0h[RD][0] + q * 4;               \
        const float zcK = (float)ZREG * LOG2E2;                             \
        {                                                                   \
            const int tn = xids[min(ph + 2, lenm1)];                        \
            ZREG = Y[(size_t)tn * HID + jt];                                \
        }                                                                   \
        float a0 = 0.f, a1 = 0.f, g0 = 0.f, g1 = 0.f;                       \
        _Pragma("unroll")                                                   \
        for (int c = 0; c < 4; ++c) {                                       \
            const uint4 hu = h0p[c];                                        \
            a0 = dot2(BCH(hu.x), whh0[0][4*c+0], a0);                       \
            a0 = dot2(BCH(hu.y), whh0[0][4*c+1], a0);                       \
            a0 = dot2(BCH(hu.z), whh0[0][4*c+2], a0);                       \
            a0 = dot2(BCH(hu.w), whh0[0][4*c+3], a0);                       \
            a1 = dot2(BCH(hu.x), whh0[1][4*c+0], a1);                       \
            a1 = dot2(BCH(hu.y), whh0[1][4*c+1], a1);                       \
            a1 = dot2(BCH(hu.z), whh0[1][4*c+2], a1);                       \
            a1 = dot2(BCH(hu.w), whh0[1][4*c+3], a1);                       \
            g0 = dot2(BCH(hu.x), wg[0][4*c+0], g0);                         \
            g0 = dot2(BCH(hu.y), wg[0][4*c+1], g0);                         \
            g0 = dot2(BCH(hu.z), wg[0][4*c+2], g0);                         \
            g0 = dot2(BCH(hu.w), wg[0][4*c+3], g0);                         \
            g1 = dot2(BCH(hu.x), wg[1][4*c+0], g1);                         \
            g1 = dot2(BCH(hu.y), wg[1][4*c+1], g1);                         \
            g1 = dot2(BCH(hu.z), wg[1][4*c+2], g1);                         \
            g1 = dot2(BCH(hu.w), wg[1][4*c+3], g1);                         \
        }                                                                   \
        const float r0 = quad_reduce(a0);                                   \
        const float r1 = quad_reduce(a1);                                   \
        const float q0 = quad_reduce(g0);                                   \
        const float q1 = quad_reduce(g1);                                   \
        if (!sel) {                                                         \
            const float r = jm ? r1 : r0;                                   \
            const float t = TANH_PRE(__builtin_fmaf(r, LOG2E2, zcK));       \
            if (ph < len) h0h[WR][jt] = (_Float16)t;                        \
        } else {                                                            \
            gh[WR][jt] = jm ? q1 : q0;                                      \
        }                                                                   \
        barrier_lds();                                                      \
    }

        for (;;) {
            A_PHASE(0, 1, zA)
            ++ph;
            if (ph > LIM) { pf = 1; break; }
            A_PHASE(1, 0, zB)
            ++ph;
            if (ph > LIM) { pf = 0; break; }
        }
#undef A_PHASE
    } else {
        // ---- B: weights Whh1, cols 2jg,2jg+1 ----
        v2h whh1[2][16];
#pragma unroll
        for (int i = 0; i < 16; ++i) {
            const int k = 32 * q + 2 * i;
#pragma unroll
            for (int m = 0; m < 2; ++m) {
                const int j = 2 * jg + m;
                whh1[m][i] = v2h{(_Float16)W_hh[HID * HID + k * HID + j],
                                 (_Float16)W_hh[HID * HID + (k + 1) * HID + j]};
            }
        }
        const float b1K = bias[HID + jt] * LOG2E2;

#define B_PHASE(RD, WR)                                                     \
    {                                                                       \
        const uint4* h1p = (const uint4*)&h1h[RD][0] + q * 4;               \
        const float gvf = gh[RD][jt];                                       \
        float a0 = 0.f, a1 = 0.f;                                           \
        _Pragma("unroll")                                                   \
        for (int c = 0; c < 4; ++c) {                                       \
            const uint4 gu = h1p[c];                                        \
            a0 = dot2(BCH(gu.x), whh1[0][4*c+0], a0);                       \
            a0 = dot2(BCH(gu.y), whh1[0][4*c+1], a0);                       \
            a0 = dot2(BCH(gu.z), whh1[0][4*c+2], a0);                       \
            a0 = dot2(BCH(gu.w), whh1[0][4*c+3], a0);                       \
            a1 = dot2(BCH(gu.x), whh1[1][4*c+0], a1);                       \
            a1 = dot2(BCH(gu.y), whh1[1][4*c+1], a1);                       \
            a1 = dot2(BCH(gu.z), whh1[1][4*c+2], a1);                       \
            a1 = dot2(BCH(gu.w), whh1[1][4*c+3], a1);                       \
        }                                                                   \
        const float r0 = quad_reduce(a0);                                   \
        const float r1 = quad_reduce(a1);                                   \
        if (!sel) {                                                         \
            const float r = (jm ? r1 : r0) + gvf;                           \
            const float t = TANH_PRE(__builtin_fmaf(r, LOG2E2, b1K));       \
            if (ph >= 2) h1h[WR][jt] = (_Float16)t;                         \
        }                                                                   \
        barrier_lds();                                                      \
    }

        for (;;) {
            B_PHASE(0, 1)
            ++ph;
            if (ph > LIM) { pf = 1; break; }
            B_PHASE(1, 0)
            ++ph;
            if (ph > LIM) { pf = 0; break; }
        }
#undef B_PHASE
    }
#undef TANH_PRE

    __syncthreads();
    // classifier: out[b] = sigmoid(h1(len-1) . cls_w + cls_b)
    if (tid < HID) red[tid] = (float)h1h[pf][tid] * cls_w[tid];
    __syncthreads();
    if (tid == 0) {
        float s = 0.f;
        for (int i = 0; i < HID; ++i) s += red[i];
        s += cls_b[0];
        out[b] = fast_rcp(1.0f + __expf(-s));
    }
}

extern "C" void kernel_launch(void* const* d_in, const int* in_sizes, int n_in,
                              void* d_out, int out_size, void* d_ws, size_t ws_size,
                              hipStream_t stream) {
    const int*   x       = (const int*)  d_in[0];
    const int*   lengths = (const int*)  d_in[1];
    const float* emb     = (const float*)d_in[2];
    const float* W_ih    = (const float*)d_in[3];
    const float* W_hh    = (const float*)d_in[4];
    const float* bias    = (const float*)d_in[5];
    const float* cls_w   = (const float*)d_in[6];
    const float* cls_b   = (const float*)d_in[7];
    float*       out     = (float*)      d_out;

    _Float16* Yws = (_Float16*)d_ws;     // 50000*128*2 B = 12.8 MB

    emb_proj_kernel<<<2048, 512, 0, stream>>>(emb, W_ih, bias, Yws);
    rnn_split_kernel<<<BATCH, NTHR, 0, stream>>>(
        x, lengths, Yws, W_ih, W_hh, bias, cls_w, cls_b, out);
}